// Round 11
// baseline (528.171 us; speedup 1.0000x reference)
//
#include <hip/hip_runtime.h>
#include <stdint.h>

#define BB 64
#define TT 2048
#define VV 512
#define TOUT 2047   // output rows per batch = T-1
#define NCH 32      // 64-visit chunks per batch row
#define CH 64
#define NSUB 128    // 16-visit sub-chunks per batch row
#define NEARLY 8    // chunk 0 split into 8 blocks of 8 visits (straggler fix)
#define EV 8

typedef unsigned long long ull;
typedef float f32x4 __attribute__((ext_vector_type(4)));

// All scratch in d_ws (~1 GiB, poison-filled by harness each iter):
//   wT      @ 0x000000 (1 MB)    W^T
//   L0e     @ 0x100000 (1 MB)    logits at early boundaries t=8x   [b][x][512]
//   L0c     @ 0x200000 (4 MB)    logits at chunk boundaries t=64c  [b][c][512]
//   Pe      @ 0x600000 (32 KB)   prefix mask at t=8x, 16 u32 each
//   Pc      @ 0x610000 (128 KB)  prefix mask at t=64c
//   submask @ 0x640000 (512 KB)  per-(b,sub) 16-visit OR masks (written uncond.)
//   stash   @ 0x700000 (8.4 MB)  per-(b,t) 512-bit visit masks, 64 B records

// ---------------- kernel A: W^T ----------------------------------------------
__global__ void k_transpose(const float* __restrict__ W, float* __restrict__ wT) {
  __shared__ float tile[32][33];
  int bx = blockIdx.x, by = blockIdx.y;
  int tx = threadIdx.x, ty = threadIdx.y;   // block (32,8)
#pragma unroll
  for (int i = 0; i < 4; ++i)
    tile[ty + i * 8][tx] = W[(size_t)(by * 32 + ty + i * 8) * VV + bx * 32 + tx];
  __syncthreads();
#pragma unroll
  for (int i = 0; i < 4; ++i)
    wT[(size_t)(bx * 32 + ty + i * 8) * VV + by * 32 + tx] = tile[tx][ty + i * 8];
}

// ---------------- kernel B: codes -> 512-bit visit masks ---------------------
// u32 word w: bit k -> v = 256(w>>3) + 128(w&1) + 4k + ((w>>1)&3)
// (word w's u64 ballot slot: sl = ((w>>3)<<2) | ((w>>1)&3), half = w&1)
__global__ void k_maskpass(const float* __restrict__ codes, const int* __restrict__ lengths,
                           uint32_t* __restrict__ stash, uint32_t* __restrict__ submask) {
  int b = blockIdx.y;
  int sub = blockIdx.x;                     // 16-visit sub-chunk
  int tid = threadIdx.x, lane = tid & 63, w = tid >> 6;
  int validB = min(lengths[b] - 1, TOUT);
  int tstart = sub * 16 + w * 4;            // wave owns 4 visits
  int n = min(4, validB - tstart);          // wave-uniform, may be <= 0
  ull o0 = 0, o1 = 0, o2 = 0, o3 = 0, o4 = 0, o5 = 0, o6 = 0, o7 = 0;
  int ww = lane & 15, s = ww >> 1;
  int jmine = lane >> 4;                    // which of the wave's 4 visits I store
  uint32_t myval = 0;
  if (n > 0) {
    const float* cp0 = codes + ((size_t)b * TT + tstart) * VV;
    f32x4 fa[4], fb[4];
#pragma unroll
    for (int j = 0; j < 4; ++j)
      if (j < n) {
        const float* cp = cp0 + (size_t)j * VV;
        fa[j] = __builtin_nontemporal_load((const f32x4*)(cp + 4 * lane));
        fb[j] = __builtin_nontemporal_load((const f32x4*)(cp + 256 + 4 * lane));
      }
#pragma unroll
    for (int j = 0; j < 4; ++j)
      if (j < n) {
        ull b0 = __ballot(fa[j][0] != 0.f);
        ull b1 = __ballot(fa[j][1] != 0.f);
        ull b2 = __ballot(fa[j][2] != 0.f);
        ull b3 = __ballot(fa[j][3] != 0.f);
        ull b4 = __ballot(fb[j][0] != 0.f);
        ull b5 = __ballot(fb[j][1] != 0.f);
        ull b6 = __ballot(fb[j][2] != 0.f);
        ull b7 = __ballot(fb[j][3] != 0.f);
        o0 |= b0; o1 |= b1; o2 |= b2; o3 |= b3;
        o4 |= b4; o5 |= b5; o6 |= b6; o7 |= b7;
        ull m01 = (s & 1) ? b1 : b0;
        ull m23 = (s & 1) ? b3 : b2;
        ull m45 = (s & 1) ? b5 : b4;
        ull m67 = (s & 1) ? b7 : b6;
        ull m03 = (s & 2) ? m23 : m01;
        ull m47 = (s & 2) ? m67 : m45;
        ull mm = (s & 4) ? m47 : m03;
        uint32_t val = (ww & 1) ? (uint32_t)(mm >> 32) : (uint32_t)mm;
        if (j == jmine) myval = val;
      }
    if (jmine < n)                          // one 256 B coalesced store per wave
      stash[((size_t)b * TOUT + tstart) * 16 + lane] = myval;
  }
  __shared__ ull red[4][8];
  if (lane == 0) {
    red[w][0] = o0; red[w][1] = o1; red[w][2] = o2; red[w][3] = o3;
    red[w][4] = o4; red[w][5] = o5; red[w][6] = o6; red[w][7] = o7;
  }
  __syncthreads();
  if (tid < 16) {                           // unconditional: every slot written
    int sl = tid >> 1, h = tid & 1;
    ull m = red[0][sl] | red[1][sl] | red[2][sl] | red[3][sl];
    uint32_t v = h ? (uint32_t)(m >> 32) : (uint32_t)m;
    int wd = ((sl >> 2) << 3) | ((sl & 3) << 1) | h;   // u64 slot/half -> u32 word
    submask[((size_t)b * NSUB + sub) * 16 + wd] = v;
  }
}

__device__ __forceinline__ int decode_v(int w, int k) {
  return ((w >> 3) << 8) | ((w & 1) << 7) | (k << 2) | ((w >> 1) & 3);
}
__device__ __forceinline__ int dec64(int s, int k) {
  return ((s >> 2) << 8) | (k << 2) | (s & 3);
}

// 4-deep pipelined column adds for one word's bits (rare events), f32x4 lanes
__device__ __forceinline__ void add_bits4(uint32_t bits, int ww, int col,
                                          const float* __restrict__ wT,
                                          f32x4& L) {
#pragma unroll 1
  while (bits) {
    int k0 = __ffs(bits) - 1; bits &= bits - 1;
    int k1 = -1, k2 = -1, k3 = -1;
    if (bits) { k1 = __ffs(bits) - 1; bits &= bits - 1; }
    if (bits) { k2 = __ffs(bits) - 1; bits &= bits - 1; }
    if (bits) { k3 = __ffs(bits) - 1; bits &= bits - 1; }
    f32x4 f0 = *(const f32x4*)(wT + (size_t)decode_v(ww, k0) * VV + col);
    f32x4 acc = f0;
    if (k1 >= 0) { f32x4 f1 = *(const f32x4*)(wT + (size_t)decode_v(ww, k1) * VV + col);
                   acc += f1; }
    if (k2 >= 0) { f32x4 f2 = *(const f32x4*)(wT + (size_t)decode_v(ww, k2) * VV + col);
                   acc += f2; }
    if (k3 >= 0) { f32x4 f3 = *(const f32x4*)(wT + (size_t)decode_v(ww, k3) * VV + col);
                   acc += f3; }
    L += acc;
  }
}

// Build wave-uniform 512-bit set from per-lane word reg (lanes 0..15 = words).
__device__ __forceinline__ void build_bs(uint32_t wreg, ull* bs) {
#pragma unroll
  for (int s2 = 0; s2 < 8; ++s2) {
    uint32_t lo = (uint32_t)__shfl((int)wreg, 2 * s2, 64);
    uint32_t hi = (uint32_t)__shfl((int)wreg, 2 * s2 + 1, 64);
    bs[s2] = ((ull)hi << 32) | lo;
  }
}

// Sum wT rows over all set bits: 8 loads in flight, 4 accumulators, f32x4
__device__ __forceinline__ void accum_bitset(const ull* bs, int col,
                                             const float* __restrict__ wT,
                                             f32x4& L) {
  f32x4 a0 = {0.f, 0.f, 0.f, 0.f}, a1 = a0, a2 = a0, a3 = a0;
  int s = 0;
  ull cur = bs[0];
#define NEXT(vk)                                        \
  do {                                                  \
    while (cur == 0 && s < 7) { ++s; cur = bs[s]; }     \
    if (cur) { int kk = __ffsll(cur) - 1; cur &= cur - 1; vk = dec64(s, kk); } \
  } while (0)
  for (;;) {
    int v0 = -1, v1 = -1, v2 = -1, v3 = -1, v4 = -1, v5 = -1, v6 = -1, v7 = -1;
    NEXT(v0); NEXT(v1); NEXT(v2); NEXT(v3);
    NEXT(v4); NEXT(v5); NEXT(v6); NEXT(v7);
    if (v0 < 0) break;
    f32x4 f0, f1, f2, f3, f4, f5, f6, f7;
    f0 = *(const f32x4*)(wT + (size_t)v0 * VV + col);
    if (v1 >= 0) f1 = *(const f32x4*)(wT + (size_t)v1 * VV + col);
    if (v2 >= 0) f2 = *(const f32x4*)(wT + (size_t)v2 * VV + col);
    if (v3 >= 0) f3 = *(const f32x4*)(wT + (size_t)v3 * VV + col);
    if (v4 >= 0) f4 = *(const f32x4*)(wT + (size_t)v4 * VV + col);
    if (v5 >= 0) f5 = *(const f32x4*)(wT + (size_t)v5 * VV + col);
    if (v6 >= 0) f6 = *(const f32x4*)(wT + (size_t)v6 * VV + col);
    if (v7 >= 0) f7 = *(const f32x4*)(wT + (size_t)v7 * VV + col);
    a0 += f0;
    if (v1 >= 0) a1 += f1;
    if (v2 >= 0) a2 += f2;
    if (v3 >= 0) a3 += f3;
    if (v4 >= 0) a0 += f4;
    if (v5 >= 0) a1 += f5;
    if (v6 >= 0) a2 += f6;
    if (v7 >= 0) a3 += f7;
    if (v7 < 0) break;
  }
#undef NEXT
  L += (a0 + a1) + (a2 + a3);
}

// ---------------- kernel C: per-b boundary-state scan ------------------------
// 64 blocks x 128 threads. Walks each batch row once, maintaining (P, L)
// incrementally; emits logits + prefix mask at every boundary k_scan needs.
__global__ void k_init(const float* __restrict__ wT, const float* __restrict__ bias,
                       const int* __restrict__ lengths,
                       const uint32_t* __restrict__ stash,
                       const uint32_t* __restrict__ submask,
                       float* __restrict__ L0e, float* __restrict__ L0c,
                       uint32_t* __restrict__ Pe, uint32_t* __restrict__ Pc) {
  int b = blockIdx.x;
  int tid = threadIdx.x, lane = tid & 63, w = tid >> 6;   // w in {0,1}
  int col = w * 256 + 4 * lane;
  int myw = lane & 15;
  int validB = min(lengths[b] - 1, TOUT);
  f32x4 L = *(const f32x4*)(bias + col);
  uint32_t Pw = 0;
  const uint32_t* st = stash + (size_t)b * TOUT * 16 + myw;
  // chunk 0 in 8-visit groups (boundaries for the early k_scan blocks)
#pragma unroll 1
  for (int g = 0; g < NEARLY; ++g) {
    *(f32x4*)(L0e + ((size_t)b * NEARLY + g) * VV + col) = L;
    if (w == 0 && lane < 16) Pe[((size_t)b * NEARLY + g) * 16 + myw] = Pw;
    int tb = g * EV;
    int ne = min(EV, validB - tb);          // may be <= 0
    if (ne > 0) {
      uint32_t vv[EV];
#pragma unroll
      for (int i = 0; i < EV; ++i) vv[i] = (i < ne) ? st[(size_t)(tb + i) * 16] : 0u;
      uint32_t om = (vv[0] | vv[1]) | (vv[2] | vv[3]) |
                    ((vv[4] | vv[5]) | (vv[6] | vv[7]));
      uint32_t cand = om & ~Pw;
      if (__ballot(cand != 0)) {
        ull cs[8]; build_bs(cand, cs);
        accum_bitset(cs, col, wT, L);
        Pw |= cand;
      }
    }
  }
  // chunks 1..31 (boundaries for the late k_scan blocks)
  const uint32_t* sm = submask + (size_t)b * NSUB * 16 + myw;
#pragma unroll 1
  for (int c = 1; c < NCH; ++c) {
    *(f32x4*)(L0c + ((size_t)b * NCH + c) * VV + col) = L;
    if (w == 0 && lane < 16) Pc[((size_t)b * NCH + c) * 16 + myw] = Pw;
    if (c == NCH - 1) break;                // last chunk's events unneeded
    int s0 = c * 4;
    uint32_t om = sm[(s0 + 0) * 16] | sm[(s0 + 1) * 16] |
                  sm[(s0 + 2) * 16] | sm[(s0 + 3) * 16];
    uint32_t cand = om & ~Pw;
    if (__ballot(cand != 0)) {
      ull cs[8]; build_bs(cand, cs);
      accum_bitset(cs, col, wT, L);
      Pw |= cand;
    }
  }
}

// ---------------- kernel D: incremental scan + store -------------------------
// 128-thread blocks: wave w owns cols [256w, 256w+256), 16 B/lane everywhere.
// grid.x = NEARLY + 31: x<8 -> 8-visit slices of chunk 0; else chunk 1..31.
// Init is now two loads (Pe/Pc word + L0e/L0c row) — no recomputation.
__global__ void k_scan(const float* __restrict__ wT, const int* __restrict__ lengths,
                       float* __restrict__ outw, const uint32_t* __restrict__ stash,
                       const float* __restrict__ L0e, const float* __restrict__ L0c,
                       const uint32_t* __restrict__ Pe, const uint32_t* __restrict__ Pc) {
  int b = blockIdx.y;
  int x = blockIdx.x;
  int tid = threadIdx.x, lane = tid & 63, w = tid >> 6;   // w in {0,1}
  int col = w * 256 + 4 * lane;             // f32x4 per lane
  int myw = lane & 15;
  int validB = min(lengths[b] - 1, TOUT);
  bool early = (x < NEARLY);
  int t0, t1;
  if (early) { t0 = x * EV; t1 = t0 + EV; }
  else {
    int sw = (x - NEARLY) + (b % 31);       // spread chunk c over CUs/XCDs
    if (sw >= 31) sw -= 31;
    t0 = (1 + sw) * CH; t1 = min(t0 + CH, TOUT);
  }
  int pe = min(t1, validB);

  if (t0 < pe) {
    uint32_t Pw;
    f32x4 L;
    if (early) {
      Pw = Pe[((size_t)b * NEARLY + x) * 16 + myw];
      L = *(const f32x4*)(L0e + ((size_t)b * NEARLY + x) * VV + col);
    } else {
      int c = t0 / CH;
      Pw = Pc[((size_t)b * NCH + c) * 16 + myw];
      L = *(const f32x4*)(L0c + ((size_t)b * NCH + c) * VV + col);
    }

    float* ob = outw + (size_t)b * TOUT * VV + col;
    const uint32_t* st = stash + (size_t)b * TOUT * 16 + myw;
    if (early) {
      int n = pe - t0;                      // <= 8 visits, all prefetched
      uint32_t vm[EV];
#pragma unroll
      for (int i = 0; i < EV; ++i)
        if (i < n) vm[i] = st[(size_t)(t0 + i) * 16];
#pragma unroll 1
      for (int i = 0; i < n; ++i) {
        uint32_t cand = vm[i] & ~Pw;
        uint32_t wwm = (uint32_t)__ballot(cand != 0) & 0xFFFFu;
        Pw |= cand;
        while (wwm) {
          int ww = __ffs(wwm) - 1; wwm &= wwm - 1;
          uint32_t nbw = (uint32_t)__shfl((int)cand, ww, 64);
          add_bits4(nbw, ww, col, wT, L);
        }
        __builtin_nontemporal_store(L, (f32x4*)(ob + (size_t)(t0 + i) * VV));
      }
    } else {
      int nfull = (pe - t0) >> 4;
      uint32_t vmr[16], vmn[16];
      if (nfull > 0) {
#pragma unroll
        for (int i = 0; i < 16; ++i) vmr[i] = st[(size_t)(t0 + i) * 16];
      }
#pragma unroll 1
      for (int ib = 0; ib < nfull; ++ib) {
        int base = t0 + ib * 16;
        if (ib + 1 < nfull) {
#pragma unroll
          for (int i = 0; i < 16; ++i) vmn[i] = st[(size_t)(base + 16 + i) * 16];
        }
#pragma unroll
        for (int i = 0; i < 16; ++i) {
          uint32_t cand = vmr[i] & ~Pw;
          uint32_t wwm = (uint32_t)__ballot(cand != 0) & 0xFFFFu;
          Pw |= cand;
          while (wwm) {                     // rare
            int ww = __ffs(wwm) - 1; wwm &= wwm - 1;
            uint32_t nbw = (uint32_t)__shfl((int)cand, ww, 64);
            add_bits4(nbw, ww, col, wT, L);
          }
          __builtin_nontemporal_store(L, (f32x4*)(ob + (size_t)(base + i) * VV));
        }
#pragma unroll
        for (int i = 0; i < 16; ++i) vmr[i] = vmn[i];
      }
#pragma unroll 1
      for (int t = t0 + nfull * 16; t < pe; ++t) {
        uint32_t cand = st[(size_t)t * 16] & ~Pw;
        uint32_t wwm = (uint32_t)__ballot(cand != 0) & 0xFFFFu;
        Pw |= cand;
        while (wwm) {
          int ww = __ffs(wwm) - 1; wwm &= wwm - 1;
          uint32_t nbw = (uint32_t)__shfl((int)cand, ww, 64);
          add_bits4(nbw, ww, col, wT, L);
        }
        __builtin_nontemporal_store(L, (f32x4*)(ob + (size_t)t * VV));
      }
    }
  }
  // --- zero rows t >= len-1 ---
  int z0 = max(t0, validB);
  if (z0 < t1) {
    size_t basep = (size_t)(b * TOUT + z0) * VV;
    size_t n = (size_t)(t1 - z0) * VV;
    f32x4 z = {0.f, 0.f, 0.f, 0.f};
    for (size_t i = (size_t)tid * 4; i < n; i += 128 * 4)
      __builtin_nontemporal_store(z, (f32x4*)(outw + basep + i));
  }
}

extern "C" void kernel_launch(void* const* d_in, const int* in_sizes, int n_in,
                              void* d_out, int out_size, void* d_ws, size_t ws_size,
                              hipStream_t stream) {
  // inputs: times[B,T] (unused), codes[B,T,V] f32, lengths[B] i32, W[V,V] f32, b[V] f32
  const float* codes = (const float*)d_in[1];
  const int* lengths = (const int*)d_in[2];
  const float* W = (const float*)d_in[3];
  const float* bias = (const float*)d_in[4];
  float* out = (float*)d_out;

  char* ws = (char*)d_ws;                          // ~1 GiB (poisoned by harness)
  float* wT = (float*)ws;                          // 1 MB
  float* L0e = (float*)(ws + 0x100000);            // 1 MB
  float* L0c = (float*)(ws + 0x200000);            // 4 MB
  uint32_t* Pe = (uint32_t*)(ws + 0x600000);       // 32 KB
  uint32_t* Pc = (uint32_t*)(ws + 0x610000);       // 128 KB
  uint32_t* submask = (uint32_t*)(ws + 0x640000);  // 512 KB
  uint32_t* stash = (uint32_t*)(ws + 0x700000);    // 8.4 MB

  k_maskpass<<<dim3(NSUB, BB), dim3(256), 0, stream>>>(codes, lengths, stash, submask);
  k_transpose<<<dim3(16, 16), dim3(32, 8), 0, stream>>>(W, wT);
  k_init<<<dim3(BB), dim3(128), 0, stream>>>(wT, bias, lengths, stash, submask,
                                             L0e, L0c, Pe, Pc);
  k_scan<<<dim3(NEARLY + 31, BB), dim3(128), 0, stream>>>(wT, lengths, out, stash,
                                                          L0e, L0c, Pe, Pc);
}

// Round 12
// 459.488 us; speedup vs baseline: 1.1495x; 1.1495x over previous
//
#include <hip/hip_runtime.h>
#include <stdint.h>

#define BB 64
#define TT 2048
#define VV 512
#define TOUT 2047   // output rows per batch = T-1
#define NCH 32      // 64-visit chunks per batch row
#define CH 64
#define NSUB 128    // 16-visit sub-chunks per batch row
#define NEARLY 8    // chunk 0 split into 8 blocks of 8 visits (straggler fix)
#define EV 8

typedef unsigned long long ull;
typedef float f32x4 __attribute__((ext_vector_type(4)));

// All scratch in d_ws (~1 GiB, poison-filled by harness each iter):
//   wT      @ 0x000000  (1 MB)    W^T
//   S       @ 0x100000  (2 KB)    bias + row-sums of W
//   submask @ 0x110000  (512 KB)  per-(b,sub) 16-visit OR masks, 64 B each,
//                                 written unconditionally (no memset needed)
//   stash   @ 0x200000  (8.4 MB)  per-(b,t) 512-bit visit masks, 64 B each
// Inputs are never written. Output is pure output.
// R11 note: hoisting boundary state into a serial 64-block k_init REGRESSED
// (+68 us) — k_scan's distributed init is latency-hidden at ~10 blocks/CU;
// keep init inside k_scan.

// ---------------- kernel A1: W^T ---------------------------------------------
__global__ void k_transpose(const float* __restrict__ W, float* __restrict__ wT) {
  __shared__ float tile[32][33];
  int bx = blockIdx.x, by = blockIdx.y;
  int tx = threadIdx.x, ty = threadIdx.y;   // block (32,8)
#pragma unroll
  for (int i = 0; i < 4; ++i)
    tile[ty + i * 8][tx] = W[(size_t)(by * 32 + ty + i * 8) * VV + bx * 32 + tx];
  __syncthreads();
#pragma unroll
  for (int i = 0; i < 4; ++i)
    wT[(size_t)(bx * 32 + ty + i * 8) * VV + by * 32 + tx] = tile[tx][ty + i * 8];
}

// ---------------- kernel A2: S[u] = bias[u] + sum_v W[u,v] -------------------
__global__ void k_rowsum(const float* __restrict__ W, const float* __restrict__ bias,
                         float* __restrict__ S) {
  int u = blockIdx.x;
  int l = threadIdx.x;
  const float* row = W + (size_t)u * VV;
  float4 a = *(const float4*)(row + 4 * l);
  float4 c = *(const float4*)(row + 256 + 4 * l);
  float s = a.x + a.y + a.z + a.w + c.x + c.y + c.z + c.w;
#pragma unroll
  for (int off = 32; off; off >>= 1) s += __shfl_xor(s, off, 64);
  if (l == 0) S[u] = bias[u] + s;
}

// ---------------- kernel B: codes -> 512-bit visit masks ---------------------
// u32 word w: bit k -> v = 256(w>>3) + 128(w&1) + 4k + ((w>>1)&3)
// (word w's u64 ballot slot: sl = ((w>>3)<<2) | ((w>>1)&3), half = w&1)
// stash record for (b,t): 16 consecutive u32 at stash[(b*TOUT+t)*16].
__global__ void k_maskpass(const float* __restrict__ codes, const int* __restrict__ lengths,
                           uint32_t* __restrict__ stash, uint32_t* __restrict__ submask) {
  int b = blockIdx.y;
  int sub = blockIdx.x;                     // 16-visit sub-chunk
  int tid = threadIdx.x, lane = tid & 63, w = tid >> 6;
  int validB = min(lengths[b] - 1, TOUT);
  int tstart = sub * 16 + w * 4;            // wave owns 4 visits
  int n = min(4, validB - tstart);          // wave-uniform, may be <= 0
  ull o0 = 0, o1 = 0, o2 = 0, o3 = 0, o4 = 0, o5 = 0, o6 = 0, o7 = 0;
  int ww = lane & 15, s = ww >> 1;
  int jmine = lane >> 4;                    // which of the wave's 4 visits I store
  uint32_t myval = 0;
  if (n > 0) {
    const float* cp0 = codes + ((size_t)b * TT + tstart) * VV;
    f32x4 fa[4], fb[4];
#pragma unroll
    for (int j = 0; j < 4; ++j)
      if (j < n) {
        const float* cp = cp0 + (size_t)j * VV;
        fa[j] = __builtin_nontemporal_load((const f32x4*)(cp + 4 * lane));
        fb[j] = __builtin_nontemporal_load((const f32x4*)(cp + 256 + 4 * lane));
      }
#pragma unroll
    for (int j = 0; j < 4; ++j)
      if (j < n) {
        ull b0 = __ballot(fa[j][0] != 0.f);
        ull b1 = __ballot(fa[j][1] != 0.f);
        ull b2 = __ballot(fa[j][2] != 0.f);
        ull b3 = __ballot(fa[j][3] != 0.f);
        ull b4 = __ballot(fb[j][0] != 0.f);
        ull b5 = __ballot(fb[j][1] != 0.f);
        ull b6 = __ballot(fb[j][2] != 0.f);
        ull b7 = __ballot(fb[j][3] != 0.f);
        o0 |= b0; o1 |= b1; o2 |= b2; o3 |= b3;
        o4 |= b4; o5 |= b5; o6 |= b6; o7 |= b7;
        // branch-free select of word ww's u64 slot: slot bits of ww (<16):
        // bit0 = (ww>>1)&1 = s&1, bit1 = (ww>>2)&1 = s&2, bit2 = (ww>>3)&1 = s&4
        ull m01 = (s & 1) ? b1 : b0;
        ull m23 = (s & 1) ? b3 : b2;
        ull m45 = (s & 1) ? b5 : b4;
        ull m67 = (s & 1) ? b7 : b6;
        ull m03 = (s & 2) ? m23 : m01;
        ull m47 = (s & 2) ? m67 : m45;
        ull mm = (s & 4) ? m47 : m03;
        uint32_t val = (ww & 1) ? (uint32_t)(mm >> 32) : (uint32_t)mm;
        if (j == jmine) myval = val;        // keep only my visit's word
      }
    // one fully-coalesced 256 B store per wave (lane = jmine*16 + ww)
    if (jmine < n)
      stash[((size_t)b * TOUT + tstart) * 16 + lane] = myval;
  }
  __shared__ ull red[4][8];
  if (lane == 0) {
    red[w][0] = o0; red[w][1] = o1; red[w][2] = o2; red[w][3] = o3;
    red[w][4] = o4; red[w][5] = o5; red[w][6] = o6; red[w][7] = o7;
  }
  __syncthreads();
  if (tid < 16) {                           // unconditional: every slot written
    int sl = tid >> 1, h = tid & 1;
    ull m = red[0][sl] | red[1][sl] | red[2][sl] | red[3][sl];
    uint32_t v = h ? (uint32_t)(m >> 32) : (uint32_t)m;
    int wd = ((sl >> 2) << 3) | ((sl & 3) << 1) | h;   // u64 slot/half -> u32 word
    submask[((size_t)b * NSUB + sub) * 16 + wd] = v;
  }
}

__device__ __forceinline__ int decode_v(int w, int k) {
  return ((w >> 3) << 8) | ((w & 1) << 7) | (k << 2) | ((w >> 1) & 3);
}
__device__ __forceinline__ int dec64(int s, int k) {
  // u64 slot s, bit k in [0,64): v = 256(s>>2) + 4k + (s&3); k>=32 supplies
  // the +128 half-word term via (k<<2).
  return ((s >> 2) << 8) | (k << 2) | (s & 3);
}

// 4-deep pipelined column adds for one word's bits (rare events), f32x4 lanes
__device__ __forceinline__ void add_bits4(uint32_t bits, int ww, int col,
                                          const float* __restrict__ wT,
                                          f32x4& L) {
#pragma unroll 1
  while (bits) {
    int k0 = __ffs(bits) - 1; bits &= bits - 1;
    int k1 = -1, k2 = -1, k3 = -1;
    if (bits) { k1 = __ffs(bits) - 1; bits &= bits - 1; }
    if (bits) { k2 = __ffs(bits) - 1; bits &= bits - 1; }
    if (bits) { k3 = __ffs(bits) - 1; bits &= bits - 1; }
    f32x4 f0 = *(const f32x4*)(wT + (size_t)decode_v(ww, k0) * VV + col);
    f32x4 acc = f0;
    if (k1 >= 0) { f32x4 f1 = *(const f32x4*)(wT + (size_t)decode_v(ww, k1) * VV + col);
                   acc += f1; }
    if (k2 >= 0) { f32x4 f2 = *(const f32x4*)(wT + (size_t)decode_v(ww, k2) * VV + col);
                   acc += f2; }
    if (k3 >= 0) { f32x4 f3 = *(const f32x4*)(wT + (size_t)decode_v(ww, k3) * VV + col);
                   acc += f3; }
    L += acc;
  }
}

// Build wave-uniform 512-bit set from per-lane word reg (lanes 0..15 = words).
// bs[s2] packs word 2*s2 (lo half) and word 2*s2+1 (hi half) -> matches dec64.
__device__ __forceinline__ void build_bs(uint32_t wreg, ull* bs) {
#pragma unroll
  for (int s2 = 0; s2 < 8; ++s2) {
    uint32_t lo = (uint32_t)__shfl((int)wreg, 2 * s2, 64);
    uint32_t hi = (uint32_t)__shfl((int)wreg, 2 * s2 + 1, 64);
    bs[s2] = ((ull)hi << 32) | lo;
  }
}

// Sum wT rows over all set bits: 8 loads in flight (init path only), f32x4
__device__ __forceinline__ void accum_bitset(const ull* bs, int col,
                                             const float* __restrict__ wT,
                                             float sign, f32x4& L) {
  f32x4 a0 = {0.f, 0.f, 0.f, 0.f}, a1 = a0, a2 = a0, a3 = a0;
  int s = 0;
  ull cur = bs[0];
#define NEXT(vk)                                        \
  do {                                                  \
    while (cur == 0 && s < 7) { ++s; cur = bs[s]; }     \
    if (cur) { int kk = __ffsll(cur) - 1; cur &= cur - 1; vk = dec64(s, kk); } \
  } while (0)
  for (;;) {
    int v0 = -1, v1 = -1, v2 = -1, v3 = -1, v4 = -1, v5 = -1, v6 = -1, v7 = -1;
    NEXT(v0); NEXT(v1); NEXT(v2); NEXT(v3);
    NEXT(v4); NEXT(v5); NEXT(v6); NEXT(v7);
    if (v0 < 0) break;
    f32x4 f0, f1, f2, f3, f4, f5, f6, f7;
    f0 = *(const f32x4*)(wT + (size_t)v0 * VV + col);
    if (v1 >= 0) f1 = *(const f32x4*)(wT + (size_t)v1 * VV + col);
    if (v2 >= 0) f2 = *(const f32x4*)(wT + (size_t)v2 * VV + col);
    if (v3 >= 0) f3 = *(const f32x4*)(wT + (size_t)v3 * VV + col);
    if (v4 >= 0) f4 = *(const f32x4*)(wT + (size_t)v4 * VV + col);
    if (v5 >= 0) f5 = *(const f32x4*)(wT + (size_t)v5 * VV + col);
    if (v6 >= 0) f6 = *(const f32x4*)(wT + (size_t)v6 * VV + col);
    if (v7 >= 0) f7 = *(const f32x4*)(wT + (size_t)v7 * VV + col);
    a0 += f0;
    if (v1 >= 0) a1 += f1;
    if (v2 >= 0) a2 += f2;
    if (v3 >= 0) a3 += f3;
    if (v4 >= 0) a0 += f4;
    if (v5 >= 0) a1 += f5;
    if (v6 >= 0) a2 += f6;
    if (v7 >= 0) a3 += f7;
    if (v7 < 0) break;
  }
#undef NEXT
  f32x4 t = (a0 + a1) + (a2 + a3);
  L += sign * t;
}

// ---------------- kernel C: incremental scan + store -------------------------
// 128-thread blocks: wave w owns cols [256w, 256w+256), 16 B/lane everywhere.
// grid.x = NEARLY + 31: x<8 -> 8-visit slices of chunk 0; else chunk 1..31.
__global__ void k_scan(const float* __restrict__ wT, const float* __restrict__ S,
                       const float* __restrict__ bias, const int* __restrict__ lengths,
                       float* __restrict__ outw, const uint32_t* __restrict__ stash,
                       const uint32_t* __restrict__ submask) {
  int b = blockIdx.y;
  int x = blockIdx.x;
  int tid = threadIdx.x, lane = tid & 63, w = tid >> 6;   // w in {0,1}
  int col = w * 256 + 4 * lane;             // f32x4 per lane
  int myw = lane & 15;
  int validB = min(lengths[b] - 1, TOUT);
  bool early = (x < NEARLY);
  int t0, t1;
  if (early) { t0 = x * EV; t1 = t0 + EV; }
  else {
    int sw = (x - NEARLY) + (b % 31);       // spread chunk c over CUs/XCDs
    if (sw >= 31) sw -= 31;
    t0 = (1 + sw) * CH; t1 = min(t0 + CH, TOUT);
  }
  int pe = min(t1, validB);

  if (t0 < pe) {
    // --- prefix P at block start ---
    uint32_t Pw = 0;
    if (early) {                            // OR per-visit stash masks t < t0
      const uint32_t* st = stash + (size_t)b * TOUT * 16 + myw;
      uint32_t q0 = 0, q1 = 0, q2 = 0, q3 = 0, q4 = 0, q5 = 0, q6 = 0, q7 = 0;
      int t = 0;
      for (; t + 8 <= t0; t += 8) {
        q0 |= st[(t + 0) * 16]; q1 |= st[(t + 1) * 16];
        q2 |= st[(t + 2) * 16]; q3 |= st[(t + 3) * 16];
        q4 |= st[(t + 4) * 16]; q5 |= st[(t + 5) * 16];
        q6 |= st[(t + 6) * 16]; q7 |= st[(t + 7) * 16];
      }
      for (; t < t0; ++t) q0 |= st[t * 16];
      Pw = (q0 | q1) | (q2 | q3) | ((q4 | q5) | (q6 | q7));
    } else {                                // OR 16-visit submasks
      const uint32_t* sm = submask + (size_t)b * NSUB * 16 + myw;
      int send = t0 >> 4;                   // sub-chunks fully before t0
      uint32_t p0 = 0, p1 = 0, p2 = 0, p3 = 0;
      int ss = 0;
      for (; ss + 4 <= send; ss += 4) {
        p0 |= sm[(ss + 0) * 16]; p1 |= sm[(ss + 1) * 16];
        p2 |= sm[(ss + 2) * 16]; p3 |= sm[(ss + 3) * 16];
      }
      for (; ss < send; ++ss) p0 |= sm[ss * 16];
      Pw = p0 | p1 | p2 | p3;
    }
    // --- init L (pipelined bitset sum, complement trick) ---
    ull bs[8];
    build_bs(Pw, bs);
    int pc = 0;
#pragma unroll
    for (int s2 = 0; s2 < 8; ++s2) pc += __popcll(bs[s2]);
    bool direct = (pc <= 256);
    f32x4 L;
    if (direct) {
      L = *(const f32x4*)(bias + col);
      accum_bitset(bs, col, wT, 1.f, L);
    } else {
      L = *(const f32x4*)(S + col);
      ull nb[8];
#pragma unroll
      for (int s2 = 0; s2 < 8; ++s2) nb[s2] = ~bs[s2];
      accum_bitset(nb, col, wT, -1.f, L);
    }

    float* ob = outw + (size_t)b * TOUT * VV + col;
    const uint32_t* st = stash + (size_t)b * TOUT * 16 + myw;
    if (early) {
      int n = pe - t0;                      // <= 8 visits, all prefetched
      uint32_t vm[EV];
#pragma unroll
      for (int i = 0; i < EV; ++i)
        if (i < n) vm[i] = st[(size_t)(t0 + i) * 16];
#pragma unroll 1
      for (int i = 0; i < n; ++i) {
        uint32_t cand = vm[i] & ~Pw;
        uint32_t wwm = (uint32_t)__ballot(cand != 0) & 0xFFFFu;
        Pw |= cand;
        while (wwm) {
          int ww = __ffs(wwm) - 1; wwm &= wwm - 1;
          uint32_t nbw = (uint32_t)__shfl((int)cand, ww, 64);
          add_bits4(nbw, ww, col, wT, L);
        }
        __builtin_nontemporal_store(L, (f32x4*)(ob + (size_t)(t0 + i) * VV));
      }
    } else {
      int nfull = (pe - t0) >> 4;
      uint32_t vmr[16], vmn[16];
      if (nfull > 0) {
#pragma unroll
        for (int i = 0; i < 16; ++i) vmr[i] = st[(size_t)(t0 + i) * 16];
      }
#pragma unroll 1
      for (int ib = 0; ib < nfull; ++ib) {
        int base = t0 + ib * 16;
        if (ib + 1 < nfull) {
#pragma unroll
          for (int i = 0; i < 16; ++i) vmn[i] = st[(size_t)(base + 16 + i) * 16];
        }
#pragma unroll
        for (int i = 0; i < 16; ++i) {
          uint32_t cand = vmr[i] & ~Pw;
          uint32_t wwm = (uint32_t)__ballot(cand != 0) & 0xFFFFu;
          Pw |= cand;
          while (wwm) {                     // rare
            int ww = __ffs(wwm) - 1; wwm &= wwm - 1;
            uint32_t nbw = (uint32_t)__shfl((int)cand, ww, 64);
            add_bits4(nbw, ww, col, wT, L);
          }
          __builtin_nontemporal_store(L, (f32x4*)(ob + (size_t)(base + i) * VV));
        }
#pragma unroll
        for (int i = 0; i < 16; ++i) vmr[i] = vmn[i];
      }
#pragma unroll 1
      for (int t = t0 + nfull * 16; t < pe; ++t) {
        uint32_t cand = st[(size_t)t * 16] & ~Pw;
        uint32_t wwm = (uint32_t)__ballot(cand != 0) & 0xFFFFu;
        Pw |= cand;
        while (wwm) {
          int ww = __ffs(wwm) - 1; wwm &= wwm - 1;
          uint32_t nbw = (uint32_t)__shfl((int)cand, ww, 64);
          add_bits4(nbw, ww, col, wT, L);
        }
        __builtin_nontemporal_store(L, (f32x4*)(ob + (size_t)t * VV));
      }
    }
  }
  // --- zero rows t >= len-1 ---
  int z0 = max(t0, validB);
  if (z0 < t1) {
    size_t basep = (size_t)(b * TOUT + z0) * VV;
    size_t n = (size_t)(t1 - z0) * VV;
    f32x4 z = {0.f, 0.f, 0.f, 0.f};
    for (size_t i = (size_t)tid * 4; i < n; i += 128 * 4)
      __builtin_nontemporal_store(z, (f32x4*)(outw + basep + i));
  }
}

extern "C" void kernel_launch(void* const* d_in, const int* in_sizes, int n_in,
                              void* d_out, int out_size, void* d_ws, size_t ws_size,
                              hipStream_t stream) {
  // inputs: times[B,T] (unused), codes[B,T,V] f32, lengths[B] i32, W[V,V] f32, b[V] f32
  const float* codes = (const float*)d_in[1];
  const int* lengths = (const int*)d_in[2];
  const float* W = (const float*)d_in[3];
  const float* bias = (const float*)d_in[4];
  float* out = (float*)d_out;

  char* ws = (char*)d_ws;                         // ~1 GiB (poison-filled by harness)
  float* wT = (float*)ws;                         // 1 MB
  float* S = (float*)(ws + 0x100000);             // 2 KB
  uint32_t* submask = (uint32_t*)(ws + 0x110000); // 512 KB
  uint32_t* stash = (uint32_t*)(ws + 0x200000);   // 8.4 MB

  k_maskpass<<<dim3(NSUB, BB), dim3(256), 0, stream>>>(codes, lengths, stash, submask);
  k_transpose<<<dim3(16, 16), dim3(32, 8), 0, stream>>>(W, wT);
  k_rowsum<<<dim3(512), dim3(64), 0, stream>>>(W, bias, S);
  k_scan<<<dim3(NEARLY + 31, BB), dim3(128), 0, stream>>>(wT, S, bias, lengths,
                                                          out, stash, submask);
}